// Round 7
// baseline (320.012 us; speedup 1.0000x reference)
//
#include <hip/hip_runtime.h>
#include <hip/hip_bf16.h>

#define NN 100000   // nodes
#define H  256      // feature dim
#define NE 300000   // edges
#define KOUT 512    // y row length (u | v)

typedef __attribute__((ext_vector_type(8))) short short8;
typedef __attribute__((ext_vector_type(8))) unsigned short ushort8v;
typedef __attribute__((ext_vector_type(4))) float f32x4;

__device__ __forceinline__ unsigned short f2bf(float f) {
    unsigned int u = __float_as_uint(f);
    u += 0x7FFFu + ((u >> 16) & 1u);   // RNE
    return (unsigned short)(u >> 16);
}
__device__ __forceinline__ float bf2f(unsigned short h) {
    return __uint_as_float(((unsigned int)h) << 16);
}
// byte offset into a [rows][64] bf16 subtile image (128B rows), XOR-swizzled
__device__ __forceinline__ int swz(int row, int coloff) {
    return row * 128 + (coloff ^ ((row & 7) << 4));
}
// async global->LDS, 16B per lane; LDS dest is wave-uniform base + lane*16
__device__ __forceinline__ void gload16(const void* g, void* l) {
    __builtin_amdgcn_global_load_lds((const __attribute__((address_space(1))) void*)g,
                                     (__attribute__((address_space(3))) void*)l,
                                     16, 0, 0);
}
__device__ __forceinline__ short8 pack8(float4 a, float4 b) {
    short8 r;
    r[0] = (short)f2bf(a.x); r[1] = (short)f2bf(a.y);
    r[2] = (short)f2bf(a.z); r[3] = (short)f2bf(a.w);
    r[4] = (short)f2bf(b.x); r[5] = (short)f2bf(b.y);
    r[6] = (short)f2bf(b.z); r[7] = (short)f2bf(b.w);
    return r;
}

// ---------------- W-prep: W1 (fp32 [512][256]) -> 16 pre-swizzled bf16 subtiles.
// t = nt*4 + ks (nt-major: one nt's 4 k-subtiles = 64KB linear).
// Subtile image: [128 n][64 k] bf16, granule (n, kg) at byte swz(n, kg*16).
// Wcat[k][j]: j<256 -> W1[k][j]; j>=256 -> W1[k+256][j-256]; j = nt*128+n, k = ks*64+kz.
__global__ __launch_bounds__(256) void wprep(const float* __restrict__ W1,
                                             unsigned short* __restrict__ wsB) {
    int gtid = blockIdx.x * 256 + threadIdx.x;   // 16384 threads (64 blocks)
    int t  = gtid >> 10;          // 0..15
    int kg = (gtid >> 7) & 7;     // 8-k group
    int n  = gtid & 127;
    int nt = t >> 2, ks = t & 3;
    int krow0 = ks * 64 + kg * 8 + ((nt >= 2) ? 256 : 0);
    int col = (nt & 1) * 128 + n;
    const float* src = W1 + (size_t)krow0 * 256 + col;
    ushort8v p;
    #pragma unroll
    for (int i = 0; i < 8; ++i) p[i] = f2bf(src[(size_t)i * 256]);
    *(ushort8v*)((char*)(wsB + t * 8192) + swz(n, kg * 16)) = p;
}

// ---------------- GEMM v7: barrier-free streaming. B (256 feats x 256 k = 128KB)
// persistent in LDS; A fragments loaded per-lane DIRECTLY from global x (8
// consecutive fp32 per lane = 2 float4), converted in-register. After the one
// B-staging barrier each wave streams 32-node strips independently: 8 waves/CU
// of continuously-in-flight loads -> HBM stays saturated.
// 256 blocks: xcd=bid&7, j=bid>>3: nt2=j&1 (feature half), chunk=xcd*16+(j>>1).
__global__ __launch_bounds__(512) void gemm_v7(const float* __restrict__ x,
                                               const unsigned short* __restrict__ wsB,
                                               unsigned short* __restrict__ y) {
    __shared__ unsigned short Bl[65536];   // 128KB: q(2) x ksub(4) x [128n][64k] swizzled
    const int tid = threadIdx.x;
    const int lane = tid & 63, wid = tid >> 6;   // 8 waves
    const int xcd = (int)blockIdx.x & 7;
    const int jj  = (int)blockIdx.x >> 3;        // 0..31
    const int nt2 = jj & 1;                      // feature half (256 feats)
    const int chunk = xcd * 16 + (jj >> 1);      // 0..127 node chunk (782 nodes)

    // ---- stage B once: 128KB linear copy (wsB tiles nt=2*nt2 and 2*nt2+1)
    {
        const char* bs = (const char*)wsB + nt2 * 131072 + wid * 16384 + lane * 16;
        char* bd = (char*)Bl + wid * 16384;
        #pragma unroll
        for (int r = 0; r < 16; ++r)
            gload16(bs + r * 1024, bd + r * 1024);
    }
    __syncthreads();   // the ONLY barrier

    const int s0 = chunk * 782;                         // first node of chunk
    const int nstrips = min(25, (NN - s0 + 31) >> 5);   // strips of 32 nodes
    const int nlo = lane & 15, ksl = lane >> 4;
    const int fbase = nt2 * 256 + ksl * 4;

    for (int s = wid; s < nstrips; s += 8) {
        const int nb = s0 + s * 32;
        int n0 = nb + nlo;      if (n0 > NN - 1) n0 = NN - 1;
        int n1 = nb + 16 + nlo; if (n1 > NN - 1) n1 = NN - 1;
        const float* xp0 = x + (size_t)n0 * H + ksl * 8;
        const float* xp1 = x + (size_t)n1 * H + ksl * 8;

        f32x4 acc[16][2];
        #pragma unroll
        for (int ni = 0; ni < 16; ++ni)
            #pragma unroll
            for (int mi = 0; mi < 2; ++mi) acc[ni][mi] = (f32x4){0.f, 0.f, 0.f, 0.f};

        // prologue A loads (ks=0)
        float4 u0 = *(const float4*)(xp0);
        float4 u1 = *(const float4*)(xp0 + 4);
        float4 v0 = *(const float4*)(xp1);
        float4 v1 = *(const float4*)(xp1 + 4);

        #pragma unroll
        for (int ks = 0; ks < 8; ++ks) {
            short8 a0 = pack8(u0, u1);
            short8 a1 = pack8(v0, v1);
            if (ks < 7) {                       // next k-chunk flies under MFMA
                u0 = *(const float4*)(xp0 + (ks + 1) * 32);
                u1 = *(const float4*)(xp0 + (ks + 1) * 32 + 4);
                v0 = *(const float4*)(xp1 + (ks + 1) * 32);
                v1 = *(const float4*)(xp1 + (ks + 1) * 32 + 4);
            }
            const int boff = (ks >> 1) * 16384 + ((ks & 1) * 64 + ksl * 16 ^ 0);
            #pragma unroll
            for (int nig = 0; nig < 4; ++nig) {
                short8 b[4];
                #pragma unroll
                for (int t4 = 0; t4 < 4; ++t4) {
                    const int ni = nig * 4 + t4;
                    const int q = ni >> 3, fn = (ni & 7) * 16 + nlo;
                    b[t4] = *(const short8*)((const char*)Bl + q * 65536 + (ks >> 1) * 16384 +
                                             swz(fn, (ks & 1) * 64 + ksl * 16));
                }
                #pragma unroll
                for (int t4 = 0; t4 < 4; ++t4) {
                    const int ni = nig * 4 + t4;
                    acc[ni][0] = __builtin_amdgcn_mfma_f32_16x16x32_bf16(b[t4], a0, acc[ni][0], 0, 0, 0);
                    acc[ni][1] = __builtin_amdgcn_mfma_f32_16x16x32_bf16(b[t4], a1, acc[ni][1], 0, 0, 0);
                }
            }
            (void)boff;
        }
        // epilogue: lane holds feats (fbase..fbase+3) of node (nb+mi*16+nlo)
        #pragma unroll
        for (int mi = 0; mi < 2; ++mi) {
            int node = nb + mi * 16 + nlo;
            if (node > NN - 1) node = NN - 1;   // duplicate write of same value: benign
            unsigned short* yp = y + (size_t)node * KOUT + fbase;
            #pragma unroll
            for (int ni = 0; ni < 16; ++ni) {
                ushort4 u;
                u.x = f2bf(acc[ni][mi][0]);
                u.y = f2bf(acc[ni][mi][1]);
                u.z = f2bf(acc[ni][mi][2]);
                u.w = f2bf(acc[ni][mi][3]);
                *(ushort4*)(yp + ni * 16) = u;
            }
        }
    }
}

// ---------------- Phase 2: half-wave per edge, ushort8 gathers
__global__ __launch_bounds__(256) void edge_v2(const unsigned short* __restrict__ y,
                                               const int* __restrict__ ei,
                                               const float* __restrict__ b1,
                                               const float* __restrict__ W2,
                                               const float* __restrict__ b2,
                                               float* __restrict__ out) {
    const int tid = threadIdx.x;
    const int l32 = tid & 31;
    const int ghw = ((int)(blockIdx.x * blockDim.x) + tid) >> 5;
    const int nhw = ((int)(gridDim.x * blockDim.x)) >> 5;
    const int j = l32 * 8;
    const float4 b01 = *(const float4*)(b1 + j);
    const float4 b23 = *(const float4*)(b1 + j + 4);
    const float4 w01 = *(const float4*)(W2 + j);
    const float4 w23 = *(const float4*)(W2 + j + 4);
    const float bb = b2[0];
    #pragma unroll 2
    for (int e = ghw; e < NE; e += nhw) {
        int s = ei[e], d = ei[NE + e];
        s = s < 0 ? 0 : (s > NN - 1 ? NN - 1 : s);
        d = d < 0 ? 0 : (d > NN - 1 ? NN - 1 : d);
        ushort8v us = *(const ushort8v*)(y + (size_t)s * KOUT + j);
        ushort8v ud = *(const ushort8v*)(y + (size_t)d * KOUT + 256 + j);
        float acc;
        acc  = fmaxf(bf2f(us[0]) + bf2f(ud[0]) + b01.x, 0.f) * w01.x;
        acc += fmaxf(bf2f(us[1]) + bf2f(ud[1]) + b01.y, 0.f) * w01.y;
        acc += fmaxf(bf2f(us[2]) + bf2f(ud[2]) + b01.z, 0.f) * w01.z;
        acc += fmaxf(bf2f(us[3]) + bf2f(ud[3]) + b01.w, 0.f) * w01.w;
        acc += fmaxf(bf2f(us[4]) + bf2f(ud[4]) + b23.x, 0.f) * w23.x;
        acc += fmaxf(bf2f(us[5]) + bf2f(ud[5]) + b23.y, 0.f) * w23.y;
        acc += fmaxf(bf2f(us[6]) + bf2f(ud[6]) + b23.z, 0.f) * w23.z;
        acc += fmaxf(bf2f(us[7]) + bf2f(ud[7]) + b23.w, 0.f) * w23.w;
        #pragma unroll
        for (int off = 16; off > 0; off >>= 1) acc += __shfl_xor(acc, off, 64);
        if (l32 == 0) out[e] = acc + bb;
    }
}

// ---------------- Fallback (ws too small): fused wave-per-edge, fp32. Slow but correct.
__global__ __launch_bounds__(256) void fused_fallback(const float* __restrict__ x,
                                                      const int* __restrict__ ei,
                                                      const float* __restrict__ W1,
                                                      const float* __restrict__ b1,
                                                      const float* __restrict__ W2,
                                                      const float* __restrict__ b2,
                                                      float* __restrict__ out) {
    __shared__ float xsh[4][512];
    const int lane = threadIdx.x & 63;
    const int wl = threadIdx.x >> 6;
    const int gw = (blockIdx.x * blockDim.x + threadIdx.x) >> 6;
    const int nw = (gridDim.x * blockDim.x) >> 6;
    const int j = lane * 4;
    const float4 bv = *(const float4*)(b1 + j);
    const float4 wv = *(const float4*)(W2 + j);
    const float bb = b2[0];
    for (int e = gw; e < NE; e += nw) {
        int s = ei[e], d = ei[NE + e];
        s = min(max(s, 0), NN - 1);
        d = min(max(d, 0), NN - 1);
        __threadfence_block();
        #pragma unroll
        for (int i = 0; i < 4; ++i) {
            xsh[wl][i * 64 + lane]       = x[(size_t)s * H + i * 64 + lane];
            xsh[wl][256 + i * 64 + lane] = x[(size_t)d * H + i * 64 + lane];
        }
        __threadfence_block();
        float h0 = bv.x, h1 = bv.y, h2 = bv.z, h3 = bv.w;
        for (int k = 0; k < 256; ++k) {
            float xa = xsh[wl][k], xb2 = xsh[wl][256 + k];
            float4 wa = *(const float4*)(W1 + (size_t)k * 256 + j);
            float4 wb = *(const float4*)(W1 + (size_t)(k + 256) * 256 + j);
            h0 += xa * wa.x + xb2 * wb.x;
            h1 += xa * wa.y + xb2 * wb.y;
            h2 += xa * wa.z + xb2 * wb.z;
            h3 += xa * wa.w + xb2 * wb.w;
        }
        float acc = fmaxf(h0, 0.f) * wv.x + fmaxf(h1, 0.f) * wv.y +
                    fmaxf(h2, 0.f) * wv.z + fmaxf(h3, 0.f) * wv.w;
        #pragma unroll
        for (int off = 32; off > 0; off >>= 1) acc += __shfl_xor(acc, off, 64);
        if (lane == 0) out[e] = acc + bb;
    }
}

extern "C" void kernel_launch(void* const* d_in, const int* in_sizes, int n_in,
                              void* d_out, int out_size, void* d_ws, size_t ws_size,
                              hipStream_t stream) {
    const float* x  = (const float*)d_in[0];
    const int*   ei = (const int*)d_in[1];
    const float* W1 = (const float*)d_in[2];
    const float* b1 = (const float*)d_in[3];
    const float* W2 = (const float*)d_in[4];
    const float* b2 = (const float*)d_in[5];
    float* out = (float*)d_out;

    const size_t ybytes = (size_t)NN * KOUT * sizeof(unsigned short);  // 102.4 MB
    const size_t wbytes = 16 * 8192 * sizeof(unsigned short);          // 256 KB

    if (ws_size >= ybytes + wbytes) {
        unsigned short* yb = (unsigned short*)d_ws;
        unsigned short* wb = (unsigned short*)((char*)d_ws + ybytes);
        wprep<<<dim3(64), dim3(256), 0, stream>>>(W1, wb);
        gemm_v7<<<dim3(256), dim3(512), 0, stream>>>(x, wb, yb);
        edge_v2<<<dim3(2048), dim3(256), 0, stream>>>(yb, ei, b1, W2, b2, out);
    } else {
        fused_fallback<<<dim3(2048), dim3(256), 0, stream>>>(x, ei, W1, b1, W2, b2, out);
    }
}

// Round 8
// 135.360 us; speedup vs baseline: 2.3642x; 2.3642x over previous
//
#include <hip/hip_runtime.h>
#include <hip/hip_bf16.h>

#define NN 100000   // nodes
#define H  256      // feature dim
#define NE 300000   // edges
#define KOUT 512    // y row length (u | v)
#define MT  782     // ceil(NN/128)

typedef __attribute__((ext_vector_type(8))) short short8;
typedef __attribute__((ext_vector_type(8))) unsigned short ushort8v;
typedef __attribute__((ext_vector_type(4))) float f32x4;

__device__ __forceinline__ unsigned short f2bf(float f) {
    unsigned int u = __float_as_uint(f);
    u += 0x7FFFu + ((u >> 16) & 1u);   // RNE
    return (unsigned short)(u >> 16);
}
__device__ __forceinline__ float bf2f(unsigned short h) {
    return __uint_as_float(((unsigned int)h) << 16);
}
// byte offset into a [rows][64] bf16 tile image (128B rows), XOR-swizzled
__device__ __forceinline__ int swz(int row, int coloff) {
    return row * 128 + (coloff ^ ((row & 7) << 4));
}
// async global->LDS, 16B per lane; LDS dest is wave-uniform base + lane*16
__device__ __forceinline__ void gload16(const void* g, void* l) {
    __builtin_amdgcn_global_load_lds((const __attribute__((address_space(1))) void*)g,
                                     (__attribute__((address_space(3))) void*)l,
                                     16, 0, 0);
}

// ---------------- W-prep: W1 (fp32 [512][256]) -> 16 pre-swizzled bf16 tiles.
// Tile t = nt*4 + ks. Image: [128 n][64 k] bf16, granule (n,kg) at byte swz(n, kg*16).
// Wcat[k][j]: j<256 -> W1[k][j]; j>=256 -> W1[k+256][j-256]; j = nt*128+n, k = ks*64+kz.
__global__ __launch_bounds__(256) void wprep(const float* __restrict__ W1,
                                             unsigned short* __restrict__ wsB) {
    int gtid = blockIdx.x * 256 + threadIdx.x;   // 16384 threads (64 blocks)
    int t  = gtid >> 10;          // 0..15
    int kg = (gtid >> 7) & 7;     // 8-k group
    int n  = gtid & 127;
    int nt = t >> 2, ks = t & 3;
    int krow0 = ks * 64 + kg * 8 + ((nt >= 2) ? 256 : 0);
    int col = (nt & 1) * 128 + n;
    const float* src = W1 + (size_t)krow0 * 256 + col;
    ushort8v p;
    #pragma unroll
    for (int i = 0; i < 8; ++i) p[i] = f2bf(src[(size_t)i * 256]);
    *(ushort8v*)((char*)(wsB + t * 8192) + swz(n, kg * 16)) = p;
}

// ---------------- X-prep v2: x (fp32 [100000][256]) -> 3128 pre-swizzled bf16 A-tiles.
// Tile t = mt*4 + ks: [128 rows][64 k] bf16, granule at swz(r, g*16). 64B in / 32B out
// per thread, fully contiguous reads. Rows >= NN duplicate node NN-1 (never consumed).
__global__ __launch_bounds__(512) void xprep2(const float* __restrict__ x,
                                              unsigned short* __restrict__ xb) {
    int gid = blockIdx.x * 512 + threadIdx.x;   // 3128*512 threads, 1 tile per block
    int t   = gid >> 9;           // tile = mt*4+ks
    int rem = gid & 511;
    int r   = rem >> 2;           // row in tile
    int gp  = (rem & 3) * 2;      // first of 2 granules (granule = 8 k-values = 16B)
    int mt = t >> 2, ks = t & 3;
    int node = mt * 128 + r; if (node > NN - 1) node = NN - 1;
    const float* src = x + (size_t)node * H + ks * 64 + gp * 8;
    float4 v0 = *(const float4*)(src);
    float4 v1 = *(const float4*)(src + 4);
    float4 v2 = *(const float4*)(src + 8);
    float4 v3 = *(const float4*)(src + 12);
    ushort8v p0, p1;
    p0[0]=f2bf(v0.x); p0[1]=f2bf(v0.y); p0[2]=f2bf(v0.z); p0[3]=f2bf(v0.w);
    p0[4]=f2bf(v1.x); p0[5]=f2bf(v1.y); p0[6]=f2bf(v1.z); p0[7]=f2bf(v1.w);
    p1[0]=f2bf(v2.x); p1[1]=f2bf(v2.y); p1[2]=f2bf(v2.z); p1[3]=f2bf(v2.w);
    p1[4]=f2bf(v3.x); p1[5]=f2bf(v3.y); p1[6]=f2bf(v3.z); p1[7]=f2bf(v3.w);
    char* dst = (char*)(xb + (size_t)t * 8192);
    *(ushort8v*)(dst + swz(r, gp * 16))      = p0;
    *(ushort8v*)(dst + swz(r, gp * 16 + 16)) = p1;
}

// ---------------- GEMM v8: m97 structure + 2-phase double-buffer.
// 128x128 tile, BK=64, 4 waves, pure global_load_lds staging from pre-swizzled
// bf16 (A from xb, B from wsB). STAGE(ks+1) issued BEFORE compute(ks) so the
// prefetch flies under ds_read+MFMA. Swapped-operand MFMA -> packed 8B stores.
__global__ __launch_bounds__(256) void gemm_v8(const unsigned short* __restrict__ xb,
                                               const unsigned short* __restrict__ wsB,
                                               unsigned short* __restrict__ y) {
    __shared__ unsigned short Al[2][8192];   // 2 x 16KB swizzled images
    __shared__ unsigned short Bl[2][8192];
    const int tid = threadIdx.x;
    // bijective XCD swizzle: grid 3128 = 8 * 391; same-mt blocks co-XCD
    const int logical = ((int)blockIdx.x & 7) * ((int)gridDim.x >> 3) + ((int)blockIdx.x >> 3);
    const int mt = logical >> 2, nt = logical & 3;
    const int m0 = mt * 128, n0 = nt * 128;
    const int lane = tid & 63, wid = tid >> 6;
    const int wm = (wid >> 1) * 64, wn = (wid & 1) * 64;
    const int lr = lane & 15, lk = lane >> 4;

    const char* asrc = (const char*)(xb + (size_t)mt * 4 * 8192) + wid * 4096 + lane * 16;
    const char* bsrc = (const char*)(wsB + nt * 4 * 8192) + wid * 4096 + lane * 16;

    f32x4 acc[4][4] = {};   // acc[ni][mi] — transposed (features x nodes)

    // prologue stage ks=0 into buf 0
    #pragma unroll
    for (int i = 0; i < 4; ++i) {
        gload16(asrc + i * 1024, (char*)Al[0] + wid * 4096 + i * 1024);
        gload16(bsrc + i * 1024, (char*)Bl[0] + wid * 4096 + i * 1024);
    }
    __syncthreads();

    #pragma unroll
    for (int ks = 0; ks < 4; ++ks) {
        // issue next-step stage FIRST: flies under this step's ds_read+MFMA
        if (ks < 3) {
            const int nb = (ks + 1) & 1;
            #pragma unroll
            for (int i = 0; i < 4; ++i) {
                gload16(asrc + (ks + 1) * 16384 + i * 1024, (char*)Al[nb] + wid * 4096 + i * 1024);
                gload16(bsrc + (ks + 1) * 16384 + i * 1024, (char*)Bl[nb] + wid * 4096 + i * 1024);
            }
        }
        const char* Ab = (const char*)Al[ks & 1];
        const char* Bb = (const char*)Bl[ks & 1];
        #pragma unroll
        for (int kk = 0; kk < 64; kk += 32) {
            const int coloff = kk * 2 + lk * 16;
            short8 a[4], b[4];
            #pragma unroll
            for (int mi = 0; mi < 4; ++mi)
                a[mi] = *(const short8*)(Ab + swz(wm + mi * 16 + lr, coloff));
            #pragma unroll
            for (int ni = 0; ni < 4; ++ni)
                b[ni] = *(const short8*)(Bb + swz(wn + ni * 16 + lr, coloff));
            #pragma unroll
            for (int ni = 0; ni < 4; ++ni)
                #pragma unroll
                for (int mi = 0; mi < 4; ++mi)
                    acc[ni][mi] = __builtin_amdgcn_mfma_f32_16x16x32_bf16(b[ni], a[mi], acc[ni][mi], 0, 0, 0);
        }
        __syncthreads();   // drains vmcnt (stage landed) + guards buf reuse
    }
    // epilogue: lane holds 4 consecutive FEATURES (lk*4..+3) of node (lr)
    #pragma unroll
    for (int mi = 0; mi < 4; ++mi) {
        const int node = m0 + wm + mi * 16 + lr;
        if (node < NN) {
            #pragma unroll
            for (int ni = 0; ni < 4; ++ni) {
                const int feat = n0 + wn + ni * 16 + lk * 4;
                ushort4 u;
                u.x = f2bf(acc[ni][mi][0]);
                u.y = f2bf(acc[ni][mi][1]);
                u.z = f2bf(acc[ni][mi][2]);
                u.w = f2bf(acc[ni][mi][3]);
                *(ushort4*)(y + (size_t)node * KOUT + feat) = u;
            }
        }
    }
}

// ---------------- Phase 2: half-wave per edge, ushort8 gathers
__global__ __launch_bounds__(256) void edge_v2(const unsigned short* __restrict__ y,
                                               const int* __restrict__ ei,
                                               const float* __restrict__ b1,
                                               const float* __restrict__ W2,
                                               const float* __restrict__ b2,
                                               float* __restrict__ out) {
    const int tid = threadIdx.x;
    const int l32 = tid & 31;
    const int ghw = ((int)(blockIdx.x * blockDim.x) + tid) >> 5;
    const int nhw = ((int)(gridDim.x * blockDim.x)) >> 5;
    const int j = l32 * 8;
    const float4 b01 = *(const float4*)(b1 + j);
    const float4 b23 = *(const float4*)(b1 + j + 4);
    const float4 w01 = *(const float4*)(W2 + j);
    const float4 w23 = *(const float4*)(W2 + j + 4);
    const float bb = b2[0];
    #pragma unroll 2
    for (int e = ghw; e < NE; e += nhw) {
        int s = ei[e], d = ei[NE + e];
        s = s < 0 ? 0 : (s > NN - 1 ? NN - 1 : s);
        d = d < 0 ? 0 : (d > NN - 1 ? NN - 1 : d);
        ushort8v us = *(const ushort8v*)(y + (size_t)s * KOUT + j);
        ushort8v ud = *(const ushort8v*)(y + (size_t)d * KOUT + 256 + j);
        float acc;
        acc  = fmaxf(bf2f(us[0]) + bf2f(ud[0]) + b01.x, 0.f) * w01.x;
        acc += fmaxf(bf2f(us[1]) + bf2f(ud[1]) + b01.y, 0.f) * w01.y;
        acc += fmaxf(bf2f(us[2]) + bf2f(ud[2]) + b01.z, 0.f) * w01.z;
        acc += fmaxf(bf2f(us[3]) + bf2f(ud[3]) + b01.w, 0.f) * w01.w;
        acc += fmaxf(bf2f(us[4]) + bf2f(ud[4]) + b23.x, 0.f) * w23.x;
        acc += fmaxf(bf2f(us[5]) + bf2f(ud[5]) + b23.y, 0.f) * w23.y;
        acc += fmaxf(bf2f(us[6]) + bf2f(ud[6]) + b23.z, 0.f) * w23.z;
        acc += fmaxf(bf2f(us[7]) + bf2f(ud[7]) + b23.w, 0.f) * w23.w;
        #pragma unroll
        for (int off = 16; off > 0; off >>= 1) acc += __shfl_xor(acc, off, 64);
        if (l32 == 0) out[e] = acc + bb;
    }
}

// ---------------- Fallback (ws too small): fused wave-per-edge, fp32. Slow but correct.
__global__ __launch_bounds__(256) void fused_fallback(const float* __restrict__ x,
                                                      const int* __restrict__ ei,
                                                      const float* __restrict__ W1,
                                                      const float* __restrict__ b1,
                                                      const float* __restrict__ W2,
                                                      const float* __restrict__ b2,
                                                      float* __restrict__ out) {
    __shared__ float xsh[4][512];
    const int lane = threadIdx.x & 63;
    const int wl = threadIdx.x >> 6;
    const int gw = (blockIdx.x * blockDim.x + threadIdx.x) >> 6;
    const int nw = (gridDim.x * blockDim.x) >> 6;
    const int j = lane * 4;
    const float4 bv = *(const float4*)(b1 + j);
    const float4 wv = *(const float4*)(W2 + j);
    const float bb = b2[0];
    for (int e = gw; e < NE; e += nw) {
        int s = ei[e], d = ei[NE + e];
        s = min(max(s, 0), NN - 1);
        d = min(max(d, 0), NN - 1);
        __threadfence_block();
        #pragma unroll
        for (int i = 0; i < 4; ++i) {
            xsh[wl][i * 64 + lane]       = x[(size_t)s * H + i * 64 + lane];
            xsh[wl][256 + i * 64 + lane] = x[(size_t)d * H + i * 64 + lane];
        }
        __threadfence_block();
        float h0 = bv.x, h1 = bv.y, h2 = bv.z, h3 = bv.w;
        for (int k = 0; k < 256; ++k) {
            float xa = xsh[wl][k], xb2 = xsh[wl][256 + k];
            float4 wa = *(const float4*)(W1 + (size_t)k * 256 + j);
            float4 wb = *(const float4*)(W1 + (size_t)(k + 256) * 256 + j);
            h0 += xa * wa.x + xb2 * wb.x;
            h1 += xa * wa.y + xb2 * wb.y;
            h2 += xa * wa.z + xb2 * wb.z;
            h3 += xa * wa.w + xb2 * wb.w;
        }
        float acc = fmaxf(h0, 0.f) * wv.x + fmaxf(h1, 0.f) * wv.y +
                    fmaxf(h2, 0.f) * wv.z + fmaxf(h3, 0.f) * wv.w;
        #pragma unroll
        for (int off = 32; off > 0; off >>= 1) acc += __shfl_xor(acc, off, 64);
        if (lane == 0) out[e] = acc + bb;
    }
}

extern "C" void kernel_launch(void* const* d_in, const int* in_sizes, int n_in,
                              void* d_out, int out_size, void* d_ws, size_t ws_size,
                              hipStream_t stream) {
    const float* x  = (const float*)d_in[0];
    const int*   ei = (const int*)d_in[1];
    const float* W1 = (const float*)d_in[2];
    const float* b1 = (const float*)d_in[3];
    const float* W2 = (const float*)d_in[4];
    const float* b2 = (const float*)d_in[5];
    float* out = (float*)d_out;

    const size_t ybytes  = (size_t)NN * KOUT * sizeof(unsigned short);  // 102.4 MB
    const size_t xbbytes = (size_t)MT * 4 * 16384;                      // 51.25 MB
    const size_t wbytes  = 16 * 8192 * sizeof(unsigned short);          // 256 KB

    if (ws_size >= ybytes + xbbytes + wbytes) {
        unsigned short* yb  = (unsigned short*)d_ws;
        unsigned short* xbb = (unsigned short*)((char*)d_ws + ybytes);
        unsigned short* wb  = (unsigned short*)((char*)d_ws + ybytes + xbbytes);
        wprep<<<dim3(64), dim3(256), 0, stream>>>(W1, wb);
        xprep2<<<dim3(MT * 4), dim3(512), 0, stream>>>(x, xbb);
        gemm_v8<<<dim3(MT * 4), dim3(256), 0, stream>>>(xbb, wb, yb);
        edge_v2<<<dim3(2048), dim3(256), 0, stream>>>(yb, ei, b1, W2, b2, out);
    } else {
        fused_fallback<<<dim3(2048), dim3(256), 0, stream>>>(x, ei, W1, b1, W2, b2, out);
    }
}